// Round 7
// baseline (303.738 us; speedup 1.0000x reference)
//
#include <hip/hip_runtime.h>
#include <hip/hip_bf16.h>

#define S_LEN 4096
#define EMBED 512
#define HEADS 8
#define HD    64

typedef short v8s __attribute__((ext_vector_type(8)));   // 8 bf16 in 4 VGPRs
typedef float v4f __attribute__((ext_vector_type(4)));
typedef float v16f __attribute__((ext_vector_type(16)));
typedef unsigned int v4u __attribute__((ext_vector_type(4)));
typedef unsigned short u16;
typedef unsigned short v4us __attribute__((ext_vector_type(4)));

// ws layout (bytes)
#define OFF_Q   0u
#define OFF_K   8388608u
#define OFF_VT  16777216u
#define OFF_AT  25165824u
#define OFF_WO  33554432u

static __device__ __forceinline__ short f2bf(float f) {
    __hip_bfloat16 h = __float2bfloat16(f);
    return __builtin_bit_cast(short, h);
}

static __device__ __forceinline__ v8s load8f_bf(const float* __restrict__ p) {
    float4 a = reinterpret_cast<const float4*>(p)[0];
    float4 b = reinterpret_cast<const float4*>(p)[1];
    v8s r;
    r[0]=f2bf(a.x); r[1]=f2bf(a.y); r[2]=f2bf(a.z); r[3]=f2bf(a.w);
    r[4]=f2bf(b.x); r[5]=f2bf(b.y); r[6]=f2bf(b.z); r[7]=f2bf(b.w);
    return r;
}

static __device__ __forceinline__ v16f zero16() {
    v16f z;
#pragma unroll
    for (int i = 0; i < 16; ++i) z[i] = 0.f;
    return z;
}

// pack two f32 -> u32 of 2 bf16 (low = lo, high = hi)
static __device__ __forceinline__ unsigned cvtpk(float lo, float hi) {
    unsigned r;
    asm volatile("v_cvt_pk_bf16_f32 %0, %1, %2" : "=v"(r) : "v"(lo), "v"(hi));
    return r;
}

// swap a's high 32 lanes with b's low 32 lanes (distinct-operand use only)
static __device__ __forceinline__ void pl32swap(unsigned &a, unsigned &b) {
    asm volatile("v_permlane32_swap_b32 %0, %1" : "+v"(a), "+v"(b));
}

// ---------------------------------------------------------------------------
// Kernel 1: per-head QKV projections (bf16 MFMA), V written TRANSPOSED.
// ---------------------------------------------------------------------------
__global__ __launch_bounds__(256) void proj_kernel(
    const float* __restrict__ xv, const float* __restrict__ xk,
    const float* __restrict__ xq,
    const float* __restrict__ Wv, const float* __restrict__ Wk,
    const float* __restrict__ Wq, const float* __restrict__ Wo,
    u16* __restrict__ q_bf, u16* __restrict__ k_bf,
    u16* __restrict__ vt_bf, u16* __restrict__ wo_bf)
{
    const int tid = threadIdx.x;
    const int lane = tid & 63;
    const int w = tid >> 6;
    const int lr = lane & 15;
    const int g  = lane >> 4;
    const int bid = blockIdx.x;
    const int bh = bid >> 6;          // b*8+h
    const int stile = bid & 63;
    const int b = bh >> 3, h = bh & 7;
    const int s0 = stile * 64;

    // Wo -> bf16
    {
        int idx = bid * 256 + tid;
        wo_bf[idx] = (u16)f2bf(Wo[idx]);
    }

    const int srow = s0 + w*16 + lr;
    const size_t xbase = ((size_t)b*S_LEN + srow)*EMBED + h*HD;
    v8s aq0 = load8f_bf(xq + xbase + g*8);
    v8s aq1 = load8f_bf(xq + xbase + 32 + g*8);
    v8s ak0 = load8f_bf(xk + xbase + g*8);
    v8s ak1 = load8f_bf(xk + xbase + 32 + g*8);
    v8s av0 = load8f_bf(xv + xbase + g*8);
    v8s av1 = load8f_bf(xv + xbase + 32 + g*8);

    const float qscale = 1.44269504088896f / 22.6274169979695f; // log2(e)/sqrt(512)
    const size_t obase = (size_t)bh * S_LEN * HD;

    // Q projection: out[s][e] = sum_d X[s][d] Wq[e][d]
#pragma unroll
    for (int et = 0; et < 4; ++et) {
        v4f acc = (v4f){0.f,0.f,0.f,0.f};
        v8s b0 = load8f_bf(Wq + (et*16 + lr)*HD + g*8);
        v8s b1 = load8f_bf(Wq + (et*16 + lr)*HD + 32 + g*8);
        acc = __builtin_amdgcn_mfma_f32_16x16x32_bf16(aq0, b0, acc, 0,0,0);
        acc = __builtin_amdgcn_mfma_f32_16x16x32_bf16(aq1, b1, acc, 0,0,0);
#pragma unroll
        for (int r = 0; r < 4; ++r) {
            int so = s0 + w*16 + g*4 + r;
            q_bf[obase + (size_t)so*HD + et*16 + lr] = (u16)f2bf(acc[r]*qscale);
        }
    }
    // K projection
#pragma unroll
    for (int et = 0; et < 4; ++et) {
        v4f acc = (v4f){0.f,0.f,0.f,0.f};
        v8s b0 = load8f_bf(Wk + (et*16 + lr)*HD + g*8);
        v8s b1 = load8f_bf(Wk + (et*16 + lr)*HD + 32 + g*8);
        acc = __builtin_amdgcn_mfma_f32_16x16x32_bf16(ak0, b0, acc, 0,0,0);
        acc = __builtin_amdgcn_mfma_f32_16x16x32_bf16(ak1, b1, acc, 0,0,0);
#pragma unroll
        for (int r = 0; r < 4; ++r) {
            int so = s0 + w*16 + g*4 + r;
            k_bf[obase + (size_t)so*HD + et*16 + lr] = (u16)f2bf(acc[r]);
        }
    }
    // V projection, SWAPPED: VT[e][s] = sum_d Wv[e][d] X[s][d]
#pragma unroll
    for (int et = 0; et < 4; ++et) {
        v4f acc = (v4f){0.f,0.f,0.f,0.f};
        v8s a0 = load8f_bf(Wv + (et*16 + lr)*HD + g*8);
        v8s a1 = load8f_bf(Wv + (et*16 + lr)*HD + 32 + g*8);
        acc = __builtin_amdgcn_mfma_f32_16x16x32_bf16(a0, av0, acc, 0,0,0);
        acc = __builtin_amdgcn_mfma_f32_16x16x32_bf16(a1, av1, acc, 0,0,0);
#pragma unroll
        for (int r = 0; r < 4; ++r) {
            int e = et*16 + g*4 + r;
            vt_bf[obase + (size_t)e*S_LEN + s0 + w*16 + lr] = (u16)f2bf(acc[r]);
        }
    }
}

// ---------------------------------------------------------------------------
// Kernel 2: flash attention, swapped-QK^T 32x32x16, O^T accumulation.
// Round-7: byte-identical math to the PASSING round 6. Single change:
// __builtin_amdgcn_sched_barrier(0) after each LOADK site and after the
// early V-load issue, so the scheduler cannot sink the prefetch loads to
// their use (round 6's VGPR=104 proved the dbuf was compiled away; round 3
// had VGPR=100 and identical 248us). Verification signal: VGPR must jump
// to ~180-220 or the prefetch was defeated again.
// ---------------------------------------------------------------------------
__global__ __launch_bounds__(256, 2) void flash_kernel(
    const u16* __restrict__ q_bf, const u16* __restrict__ k_bf,
    const u16* __restrict__ vt_bf, u16* __restrict__ attn_buf)
{
    const int tid = threadIdx.x;
    const int lane = tid & 63;
    const int w = tid >> 6;
    const int l31 = lane & 31;
    const int hi = lane >> 5;

    // bijective XCD swizzle (nwg=512, %8==0): 64 consecutive wg per XCD
    // -> 2 heads per XCD -> K+VT (2 MB) fit the 4 MB XCD L2.
    const int orig = blockIdx.x;
    const int wg = (orig & 7) * 64 + (orig >> 3);
    const int bh = wg >> 5;
    const int qt = wg & 31;
    const int s0 = qt * 128 + w * 32;

    const u16* __restrict__ Q  = q_bf  + (size_t)bh * S_LEN * HD;
    const u16* __restrict__ K  = k_bf  + (size_t)bh * S_LEN * HD;
    const u16* __restrict__ VT = vt_bf + (size_t)bh * HD * S_LEN;

    // Q B-frags (held for the whole kernel): col q=l31, k=d chunk
    v8s qf[4];
#pragma unroll
    for (int dc = 0; dc < 4; ++dc)
        qf[dc] = *(const v8s*)(Q + (size_t)(s0 + l31)*HD + dc*16 + hi*8);

    v16f o0 = zero16(), o1 = zero16();   // O^T: rows d 0-31 / 32-63, col q=l31
    float m = -1.0e30f, lsum = 0.f;      // FULL-row lsum (round-3 semantics)

// ---- K frag loads for tile KB into KF0/KF1 (8 x dwordx4 from L2) ----------
#define LOADK(KF0, KF1, KB) do {                                              \
    const u16* _k0p = K + (size_t)((KB)*64 + l31)*HD + hi*8;                  \
    _Pragma("unroll")                                                         \
    for (int dc = 0; dc < 4; ++dc) {                                          \
        KF0[dc] = *(const v8s*)(_k0p + dc*16);                                \
        KF1[dc] = *(const v8s*)(_k0p + 32*HD + dc*16);                        \
    }                                                                         \
    __builtin_amdgcn_sched_barrier(0); /* pin: do not sink these loads */     \
    } while (0)

// ---- one kv-tile body using K frags KF0/KF1 (round-3-exact math) ----------
#define BODY(KF0, KF1, KB) do {                                               \
    const int _kv0 = (KB) * 64;                                               \
    /* V^T A-frags: issued early, consumed after softmax */                   \
    v8s _vf0[4], _vf1[4];                                                     \
    {                                                                         \
        const u16* _vp = VT + (size_t)l31*S_LEN + _kv0 + hi*8;                \
        _Pragma("unroll")                                                     \
        for (int c = 0; c < 4; ++c) {                                         \
            _vf0[c] = *(const v8s*)(_vp + c*16);                              \
            _vf1[c] = *(const v8s*)(_vp + 32*S_LEN + c*16);                   \
        }                                                                     \
    }                                                                         \
    __builtin_amdgcn_sched_barrier(0); /* pin: V loads issue before QK^T */   \
    /* QK^T (swapped): S^T[kv][q] */                                          \
    v16f _s0 = zero16(), _s1 = zero16();                                      \
    __builtin_amdgcn_s_setprio(1);                                            \
    _Pragma("unroll")                                                         \
    for (int dc = 0; dc < 4; ++dc) {                                          \
        _s0 = __builtin_amdgcn_mfma_f32_32x32x16_bf16(KF0[dc], qf[dc], _s0, 0,0,0); \
        _s1 = __builtin_amdgcn_mfma_f32_32x32x16_bf16(KF1[dc], qf[dc], _s1, 0,0,0); \
    }                                                                         \
    __builtin_amdgcn_s_setprio(0);                                            \
    /* per-lane max over own 32 kv: balanced tree */                          \
    float _tm[8];                                                             \
    _Pragma("unroll")                                                         \
    for (int r = 0; r < 8; ++r)                                               \
        _tm[r] = fmaxf(fmaxf(_s0[r], _s0[r+8]), fmaxf(_s1[r], _s1[r+8]));     \
    _Pragma("unroll")                                                         \
    for (int st = 4; st; st >>= 1)                                            \
        _Pragma("unroll")                                                     \
        for (int r = 0; r < st; ++r) _tm[r] = fmaxf(_tm[r], _tm[r+st]);       \
    /* cross-half max via shfl_xor, unconditional rescale (round-3 exact) */  \
    float _tmax = fmaxf(_tm[0], __shfl_xor(_tm[0], 32));                      \
    const float _mn = fmaxf(m, _tmax);                                        \
    const float _corr = __builtin_amdgcn_exp2f(m - _mn);                      \
    m = _mn;                                                                  \
    /* P = exp2(S - m), round-3 exact loop and chain order */                 \
    float _psA = 0.f, _psB = 0.f;                                             \
    _Pragma("unroll")                                                         \
    for (int r = 0; r < 16; ++r) {                                            \
        _s0[r] = __builtin_amdgcn_exp2f(_s0[r] - m);                          \
        _s1[r] = __builtin_amdgcn_exp2f(_s1[r] - m);                          \
        _psA += _s0[r];                                                       \
        _psB += _s1[r];                                                       \
    }                                                                         \
    float _ps = _psA + _psB;                                                  \
    _ps += __shfl_xor(_ps, 32);                                               \
    lsum = lsum * _corr + _ps;                                                \
    /* rescale O^T: col q = l31 for every register -> per-lane mul */         \
    _Pragma("unroll")                                                         \
    for (int r = 0; r < 16; ++r) { o0[r] *= _corr; o1[r] *= _corr; }          \
    /* P -> bf16 frags (T12): reg r holds kv=(r&3)+8*(r>>2)+4*hi; chunk c     \
       needs kv = c*16 + hi*8 + j as 4 u32 words */                           \
    v8s _pa[4];                                                               \
    _Pragma("unroll")                                                         \
    for (int c = 0; c < 4; ++c) {                                             \
        const int _rb = (c & 1) * 8;                                          \
        unsigned _x0, _x1, _x2, _x3;                                          \
        if (c < 2) {                                                          \
            _x0 = cvtpk(_s0[_rb+0], _s0[_rb+1]);                              \
            _x1 = cvtpk(_s0[_rb+2], _s0[_rb+3]);                              \
            _x2 = cvtpk(_s0[_rb+4], _s0[_rb+5]);                              \
            _x3 = cvtpk(_s0[_rb+6], _s0[_rb+7]);                              \
        } else {                                                              \
            _x0 = cvtpk(_s1[_rb+0], _s1[_rb+1]);                              \
            _x1 = cvtpk(_s1[_rb+2], _s1[_rb+3]);                              \
            _x2 = cvtpk(_s1[_rb+4], _s1[_rb+5]);                              \
            _x3 = cvtpk(_s1[_rb+6], _s1[_rb+7]);                              \
        }                                                                     \
        pl32swap(_x0, _x2);                                                   \
        pl32swap(_x1, _x3);                                                   \
        v4u _u; _u[0]=_x0; _u[1]=_x1; _u[2]=_x2; _u[3]=_x3;                   \
        _pa[c] = __builtin_bit_cast(v8s, _u);                                 \
    }                                                                         \
    /* PV transposed: O^T[d][q] += V^T[d][kv] * P^T[kv][q] */                 \
    __builtin_amdgcn_s_setprio(1);                                            \
    _Pragma("unroll")                                                         \
    for (int c = 0; c < 4; ++c) {                                             \
        o0 = __builtin_amdgcn_mfma_f32_32x32x16_bf16(_vf0[c], _pa[c], o0, 0,0,0); \
        o1 = __builtin_amdgcn_mfma_f32_32x32x16_bf16(_vf1[c], _pa[c], o1, 0,0,0); \
    }                                                                         \
    __builtin_amdgcn_s_setprio(0);                                            \
} while (0)

    v8s kA0[4], kA1[4], kB0[4], kB1[4];
    LOADK(kA0, kA1, 0);
    for (int kb = 0; kb < S_LEN/64; kb += 2) {
        LOADK(kB0, kB1, kb + 1);        // prefetch odd tile
        BODY(kA0, kA1, kb);             // compute even tile
        LOADK(kA0, kA1, (kb + 2) & 63); // prefetch next even (wraps harmlessly)
        BODY(kB0, kB1, kb + 1);         // compute odd tile
    }
#undef LOADK
#undef BODY

    // epilogue: normalize (per-lane, q = l31; lsum already full-row) and
    // write attn_buf[b][s0+l31][h*64 + d], d = (r&3)+8*(r>>2)+4*hi.
    const int b = bh >> 3, h = bh & 7;
    const float inv = __builtin_amdgcn_rcpf(lsum);
    const size_t base = ((size_t)b * S_LEN + s0 + l31) * EMBED + h * HD;
#pragma unroll
    for (int c = 0; c < 4; ++c) {
        const int d0 = c*8 + hi*4;
        v4us p0, p1;
#pragma unroll
        for (int i = 0; i < 4; ++i) {
            p0[i] = (u16)f2bf(o0[c*4+i] * inv);
            p1[i] = (u16)f2bf(o1[c*4+i] * inv);
        }
        *(v4us*)(attn_buf + base + d0)      = p0;
        *(v4us*)(attn_buf + base + 32 + d0) = p1;
    }
}

// ---------------------------------------------------------------------------
// Kernel 3: out = attn_buf @ Wo^T + bo  (M=8192, N=512, K=512), fp32 out.
// ---------------------------------------------------------------------------
__global__ __launch_bounds__(256) void oproj_kernel(
    const u16* __restrict__ attn_buf, const u16* __restrict__ wo_bf,
    const float* __restrict__ bo, float* __restrict__ out)
{
    const int tid = threadIdx.x;
    const int lane = tid & 63;
    const int w = tid >> 6;
    const int lr = lane & 15;
    const int g  = lane >> 4;
    const int bid = blockIdx.x;
    const int m0 = (bid >> 3)*64 + w*16;
    const int n0 = (bid & 7)*64;

    v4f acc[4];
#pragma unroll
    for (int i = 0; i < 4; ++i) acc[i] = (v4f){0.f,0.f,0.f,0.f};

    for (int kk = 0; kk < EMBED/32; ++kk) {
        const int k0 = kk*32;
        v8s af = *(const v8s*)(attn_buf + (size_t)(m0+lr)*EMBED + k0 + g*8);
#pragma unroll
        for (int nt = 0; nt < 4; ++nt) {
            v8s bf = *(const v8s*)(wo_bf + (size_t)(n0 + nt*16 + lr)*EMBED + k0 + g*8);
            acc[nt] = __builtin_amdgcn_mfma_f32_16x16x32_bf16(af, bf, acc[nt], 0,0,0);
        }
    }
#pragma unroll
    for (int nt = 0; nt < 4; ++nt) {
        float bias = bo[n0 + nt*16 + lr];
#pragma unroll
        for (int r = 0; r < 4; ++r) {
            out[(size_t)(m0 + g*4 + r)*EMBED + n0 + nt*16 + lr] = acc[nt][r] + bias;
        }
    }
}

extern "C" void kernel_launch(void* const* d_in, const int* in_sizes, int n_in,
                              void* d_out, int out_size, void* d_ws, size_t ws_size,
                              hipStream_t stream)
{
    const float* xv = (const float*)d_in[0];   // values
    const float* xk = (const float*)d_in[1];   // keys
    const float* xq = (const float*)d_in[2];   // query
    const float* Wv = (const float*)d_in[3];
    const float* Wk = (const float*)d_in[4];
    const float* Wq = (const float*)d_in[5];
    const float* Wo = (const float*)d_in[6];
    const float* bo = (const float*)d_in[7];

    char* ws = (char*)d_ws;
    u16* q_bf   = (u16*)(ws + OFF_Q);
    u16* k_bf   = (u16*)(ws + OFF_K);
    u16* vt_bf  = (u16*)(ws + OFF_VT);
    u16* at_buf = (u16*)(ws + OFF_AT);
    u16* wo_bf  = (u16*)(ws + OFF_WO);

    proj_kernel<<<1024, 256, 0, stream>>>(xv, xk, xq, Wv, Wk, Wq, Wo,
                                          q_bf, k_bf, vt_bf, wo_bf);
    flash_kernel<<<512, 256, 0, stream>>>(q_bf, k_bf, vt_bf, at_buf);
    oproj_kernel<<<1024, 256, 0, stream>>>(at_buf, wo_bf, bo, (float*)d_out);
}

// Round 8
// 169.197 us; speedup vs baseline: 1.7952x; 1.7952x over previous
//
#include <hip/hip_runtime.h>
#include <hip/hip_bf16.h>

#define S_LEN 4096
#define EMBED 512
#define HEADS 8
#define HD    64

typedef short v8s __attribute__((ext_vector_type(8)));   // 8 bf16 in 4 VGPRs
typedef float v4f __attribute__((ext_vector_type(4)));
typedef float v16f __attribute__((ext_vector_type(16)));
typedef unsigned int v4u __attribute__((ext_vector_type(4)));
typedef unsigned short u16;
typedef unsigned short v4us __attribute__((ext_vector_type(4)));

// ws layout (bytes)
#define OFF_Q   0u
#define OFF_K   8388608u
#define OFF_VT  16777216u
#define OFF_AT  25165824u
#define OFF_WO  33554432u

static __device__ __forceinline__ short f2bf(float f) {
    __hip_bfloat16 h = __float2bfloat16(f);
    return __builtin_bit_cast(short, h);
}

static __device__ __forceinline__ v8s load8f_bf(const float* __restrict__ p) {
    float4 a = reinterpret_cast<const float4*>(p)[0];
    float4 b = reinterpret_cast<const float4*>(p)[1];
    v8s r;
    r[0]=f2bf(a.x); r[1]=f2bf(a.y); r[2]=f2bf(a.z); r[3]=f2bf(a.w);
    r[4]=f2bf(b.x); r[5]=f2bf(b.y); r[6]=f2bf(b.z); r[7]=f2bf(b.w);
    return r;
}

static __device__ __forceinline__ v16f zero16() {
    v16f z;
#pragma unroll
    for (int i = 0; i < 16; ++i) z[i] = 0.f;
    return z;
}

// pack two f32 -> u32 of 2 bf16 (low = lo, high = hi)
static __device__ __forceinline__ unsigned cvtpk(float lo, float hi) {
    unsigned r;
    asm volatile("v_cvt_pk_bf16_f32 %0, %1, %2" : "=v"(r) : "v"(lo), "v"(hi));
    return r;
}

// swap a's high 32 lanes with b's low 32 lanes (distinct-operand use only)
static __device__ __forceinline__ void pl32swap(unsigned &a, unsigned &b) {
    asm volatile("v_permlane32_swap_b32 %0, %1" : "+v"(a), "+v"(b));
}

// ---------------------------------------------------------------------------
// Kernel 1: per-head QKV projections (bf16 MFMA).
// Round-8: K and V are written in MFMA-FRAGMENT-LINEAR layout so the flash
// kernel's loads are perfectly coalesced (base + lane*16B, 1KB/instr):
//   kfrag[bh][t32][dc][lane][8]:  elem (kv,d) -> t32=kv>>5, dc=d>>4,
//                                 lane=((d>>3)&1)*32 + (kv&31), j=d&7
//   vfrag[bh][kvt64][dhalf][c][lane][8]: elem (d,kv) -> kvt64=kv>>6,
//            dhalf=d>>5, c=(kv>>4)&3, lane=((kv>>3)&1)*32 + (d&31), j=kv&7
// Q keeps row-major [bh][s][64] (loaded once per wave). Wo cast to bf16.
// ---------------------------------------------------------------------------
__global__ __launch_bounds__(256) void proj_kernel(
    const float* __restrict__ xv, const float* __restrict__ xk,
    const float* __restrict__ xq,
    const float* __restrict__ Wv, const float* __restrict__ Wk,
    const float* __restrict__ Wq, const float* __restrict__ Wo,
    u16* __restrict__ q_bf, u16* __restrict__ k_bf,
    u16* __restrict__ vt_bf, u16* __restrict__ wo_bf)
{
    const int tid = threadIdx.x;
    const int lane = tid & 63;
    const int w = tid >> 6;
    const int lr = lane & 15;
    const int g  = lane >> 4;
    const int bid = blockIdx.x;
    const int bh = bid >> 6;          // b*8+h
    const int stile = bid & 63;
    const int b = bh >> 3, h = bh & 7;
    const int s0 = stile * 64;

    // Wo -> bf16
    {
        int idx = bid * 256 + tid;
        wo_bf[idx] = (u16)f2bf(Wo[idx]);
    }

    const int srow = s0 + w*16 + lr;
    const size_t xbase = ((size_t)b*S_LEN + srow)*EMBED + h*HD;
    v8s aq0 = load8f_bf(xq + xbase + g*8);
    v8s aq1 = load8f_bf(xq + xbase + 32 + g*8);
    v8s ak0 = load8f_bf(xk + xbase + g*8);
    v8s ak1 = load8f_bf(xk + xbase + 32 + g*8);
    v8s av0 = load8f_bf(xv + xbase + g*8);
    v8s av1 = load8f_bf(xv + xbase + 32 + g*8);

    const float qscale = 1.44269504088896f / 22.6274169979695f; // log2(e)/sqrt(512)
    const size_t obase = (size_t)bh * S_LEN * HD;

    // Q projection: out[s][e] = sum_d X[s][d] Wq[e][d]  (row-major)
#pragma unroll
    for (int et = 0; et < 4; ++et) {
        v4f acc = (v4f){0.f,0.f,0.f,0.f};
        v8s b0 = load8f_bf(Wq + (et*16 + lr)*HD + g*8);
        v8s b1 = load8f_bf(Wq + (et*16 + lr)*HD + 32 + g*8);
        acc = __builtin_amdgcn_mfma_f32_16x16x32_bf16(aq0, b0, acc, 0,0,0);
        acc = __builtin_amdgcn_mfma_f32_16x16x32_bf16(aq1, b1, acc, 0,0,0);
#pragma unroll
        for (int r = 0; r < 4; ++r) {
            int so = s0 + w*16 + g*4 + r;
            q_bf[obase + (size_t)so*HD + et*16 + lr] = (u16)f2bf(acc[r]*qscale);
        }
    }
    // K projection -> fragment-linear kfrag
#pragma unroll
    for (int et = 0; et < 4; ++et) {
        v4f acc = (v4f){0.f,0.f,0.f,0.f};
        v8s b0 = load8f_bf(Wk + (et*16 + lr)*HD + g*8);
        v8s b1 = load8f_bf(Wk + (et*16 + lr)*HD + 32 + g*8);
        acc = __builtin_amdgcn_mfma_f32_16x16x32_bf16(ak0, b0, acc, 0,0,0);
        acc = __builtin_amdgcn_mfma_f32_16x16x32_bf16(ak1, b1, acc, 0,0,0);
#pragma unroll
        for (int r = 0; r < 4; ++r) {
            int kv = s0 + w*16 + g*4 + r;     // row
            // d = et*16 + lr
            int idx = (((bh*128 + (kv>>5))*4 + et)*64
                       + ((lr>>3)&1)*32 + (kv&31))*8 + (lr&7);
            k_bf[idx] = (u16)f2bf(acc[r]);
        }
    }
    // V projection, SWAPPED (acc = VT[e][s]) -> fragment-linear vfrag
#pragma unroll
    for (int et = 0; et < 4; ++et) {
        v4f acc = (v4f){0.f,0.f,0.f,0.f};
        v8s a0 = load8f_bf(Wv + (et*16 + lr)*HD + g*8);
        v8s a1 = load8f_bf(Wv + (et*16 + lr)*HD + 32 + g*8);
        acc = __builtin_amdgcn_mfma_f32_16x16x32_bf16(a0, av0, acc, 0,0,0);
        acc = __builtin_amdgcn_mfma_f32_16x16x32_bf16(a1, av1, acc, 0,0,0);
#pragma unroll
        for (int r = 0; r < 4; ++r) {
            int d  = et*16 + g*4 + r;
            int kv = s0 + w*16 + lr;
            int idx = ((((bh*64 + (kv>>6))*2 + (d>>5))*4 + ((kv>>4)&3))*64
                       + ((kv>>3)&1)*32 + (d&31))*8 + (kv&7);
            vt_bf[idx] = (u16)f2bf(acc[r]);
        }
    }
}

// ---------------------------------------------------------------------------
// Kernel 2: flash attention, swapped-QK^T 32x32x16, O^T accumulation.
// Round-8: math byte-identical to passing rounds 6/7. Only change: K/V frag
// loads now read the fragment-linear layout -- every load is base+lane*16B
// (8 cache lines/instr instead of 32). K register double-buffer retained.
// ---------------------------------------------------------------------------
__global__ __launch_bounds__(256, 2) void flash_kernel(
    const u16* __restrict__ q_bf, const u16* __restrict__ k_bf,
    const u16* __restrict__ vt_bf, u16* __restrict__ attn_buf)
{
    const int tid = threadIdx.x;
    const int lane = tid & 63;
    const int w = tid >> 6;
    const int l31 = lane & 31;
    const int hi = lane >> 5;

    // bijective XCD swizzle (nwg=512, %8==0): 64 consecutive wg per XCD
    // -> 2 heads per XCD -> K+V frag buffers (2 MB) fit the 4 MB XCD L2.
    const int orig = blockIdx.x;
    const int wg = (orig & 7) * 64 + (orig >> 3);
    const int bh = wg >> 5;
    const int qt = wg & 31;
    const int s0 = qt * 128 + w * 32;

    const u16* __restrict__ Q = q_bf + (size_t)bh * S_LEN * HD;
    const v8s* __restrict__ KFp = (const v8s*)(k_bf)  + (size_t)bh * 32768;
    const v8s* __restrict__ VFp = (const v8s*)(vt_bf) + (size_t)bh * 32768;

    // Q B-frags (held for the whole kernel): col q=l31, k=d chunk
    v8s qf[4];
#pragma unroll
    for (int dc = 0; dc < 4; ++dc)
        qf[dc] = *(const v8s*)(Q + (size_t)(s0 + l31)*HD + dc*16 + hi*8);

    v16f o0 = zero16(), o1 = zero16();   // O^T: rows d 0-31 / 32-63, col q=l31
    float m = -1.0e30f, lsum = 0.f;      // FULL-row lsum (round-3 semantics)

// ---- K frag loads for 64-kv tile KB: 8 contiguous 1KB loads ---------------
#define LOADK(KF0, KF1, KB) do {                                              \
    const v8s* _kp = KFp + (size_t)(KB)*512 + lane;                           \
    _Pragma("unroll")                                                         \
    for (int dc = 0; dc < 4; ++dc) {                                          \
        KF0[dc] = _kp[dc*64];                                                 \
        KF1[dc] = _kp[256 + dc*64];                                           \
    }                                                                         \
    __builtin_amdgcn_sched_barrier(0); /* pin: do not sink these loads */     \
    } while (0)

// ---- one kv-tile body using K frags KF0/KF1 (round-3-exact math) ----------
#define BODY(KF0, KF1, KB) do {                                               \
    /* V^T A-frags: 8 contiguous 1KB loads; issued early, used after SM */    \
    v8s _vf0[4], _vf1[4];                                                     \
    {                                                                         \
        const v8s* _vp = VFp + (size_t)(KB)*512 + lane;                       \
        _Pragma("unroll")                                                     \
        for (int c = 0; c < 4; ++c) {                                         \
            _vf0[c] = _vp[c*64];                                              \
            _vf1[c] = _vp[256 + c*64];                                        \
        }                                                                     \
    }                                                                         \
    __builtin_amdgcn_sched_barrier(0); /* pin: V loads issue before QK^T */   \
    /* QK^T (swapped): S^T[kv][q] */                                          \
    v16f _s0 = zero16(), _s1 = zero16();                                      \
    __builtin_amdgcn_s_setprio(1);                                            \
    _Pragma("unroll")                                                         \
    for (int dc = 0; dc < 4; ++dc) {                                          \
        _s0 = __builtin_amdgcn_mfma_f32_32x32x16_bf16(KF0[dc], qf[dc], _s0, 0,0,0); \
        _s1 = __builtin_amdgcn_mfma_f32_32x32x16_bf16(KF1[dc], qf[dc], _s1, 0,0,0); \
    }                                                                         \
    __builtin_amdgcn_s_setprio(0);                                            \
    /* per-lane max over own 32 kv: balanced tree */                          \
    float _tm[8];                                                             \
    _Pragma("unroll")                                                         \
    for (int r = 0; r < 8; ++r)                                               \
        _tm[r] = fmaxf(fmaxf(_s0[r], _s0[r+8]), fmaxf(_s1[r], _s1[r+8]));     \
    _Pragma("unroll")                                                         \
    for (int st = 4; st; st >>= 1)                                            \
        _Pragma("unroll")                                                     \
        for (int r = 0; r < st; ++r) _tm[r] = fmaxf(_tm[r], _tm[r+st]);       \
    /* cross-half max via shfl_xor, unconditional rescale (round-3 exact) */  \
    float _tmax = fmaxf(_tm[0], __shfl_xor(_tm[0], 32));                      \
    const float _mn = fmaxf(m, _tmax);                                        \
    const float _corr = __builtin_amdgcn_exp2f(m - _mn);                      \
    m = _mn;                                                                  \
    /* P = exp2(S - m), round-3 exact loop and chain order */                 \
    float _psA = 0.f, _psB = 0.f;                                             \
    _Pragma("unroll")                                                         \
    for (int r = 0; r < 16; ++r) {                                            \
        _s0[r] = __builtin_amdgcn_exp2f(_s0[r] - m);                          \
        _s1[r] = __builtin_amdgcn_exp2f(_s1[r] - m);                          \
        _psA += _s0[r];                                                       \
        _psB += _s1[r];                                                       \
    }                                                                         \
    float _ps = _psA + _psB;                                                  \
    _ps += __shfl_xor(_ps, 32);                                               \
    lsum = lsum * _corr + _ps;                                                \
    /* rescale O^T: col q = l31 for every register -> per-lane mul */         \
    _Pragma("unroll")                                                         \
    for (int r = 0; r < 16; ++r) { o0[r] *= _corr; o1[r] *= _corr; }          \
    /* P -> bf16 frags (T12): reg r holds kv=(r&3)+8*(r>>2)+4*hi; chunk c     \
       needs kv = c*16 + hi*8 + j as 4 u32 words */                           \
    v8s _pa[4];                                                               \
    _Pragma("unroll")                                                         \
    for (int c = 0; c < 4; ++c) {                                             \
        const int _rb = (c & 1) * 8;                                          \
        unsigned _x0, _x1, _x2, _x3;                                          \
        if (c < 2) {                                                          \
            _x0 = cvtpk(_s0[_rb+0], _s0[_rb+1]);                              \
            _x1 = cvtpk(_s0[_rb+2], _s0[_rb+3]);                              \
            _x2 = cvtpk(_s0[_rb+4], _s0[_rb+5]);                              \
            _x3 = cvtpk(_s0[_rb+6], _s0[_rb+7]);                              \
        } else {                                                              \
            _x0 = cvtpk(_s1[_rb+0], _s1[_rb+1]);                              \
            _x1 = cvtpk(_s1[_rb+2], _s1[_rb+3]);                              \
            _x2 = cvtpk(_s1[_rb+4], _s1[_rb+5]);                              \
            _x3 = cvtpk(_s1[_rb+6], _s1[_rb+7]);                              \
        }                                                                     \
        pl32swap(_x0, _x2);                                                   \
        pl32swap(_x1, _x3);                                                   \
        v4u _u; _u[0]=_x0; _u[1]=_x1; _u[2]=_x2; _u[3]=_x3;                   \
        _pa[c] = __builtin_bit_cast(v8s, _u);                                 \
    }                                                                         \
    /* PV transposed: O^T[d][q] += V^T[d][kv] * P^T[kv][q] */                 \
    __builtin_amdgcn_s_setprio(1);                                            \
    _Pragma("unroll")                                                         \
    for (int c = 0; c < 4; ++c) {                                             \
        o0 = __builtin_amdgcn_mfma_f32_32x32x16_bf16(_vf0[c], _pa[c], o0, 0,0,0); \
        o1 = __builtin_amdgcn_mfma_f32_32x32x16_bf16(_vf1[c], _pa[c], o1, 0,0,0); \
    }                                                                         \
    __builtin_amdgcn_s_setprio(0);                                            \
} while (0)

    v8s kA0[4], kA1[4], kB0[4], kB1[4];
    LOADK(kA0, kA1, 0);
    for (int kb = 0; kb < S_LEN/64; kb += 2) {
        LOADK(kB0, kB1, kb + 1);        // prefetch odd tile
        BODY(kA0, kA1, kb);             // compute even tile
        LOADK(kA0, kA1, (kb + 2) & 63); // prefetch next even (wraps harmlessly)
        BODY(kB0, kB1, kb + 1);         // compute odd tile
    }
#undef LOADK
#undef BODY

    // epilogue: normalize (per-lane, q = l31; lsum already full-row) and
    // write attn_buf[b][s0+l31][h*64 + d], d = (r&3)+8*(r>>2)+4*hi.
    const int b = bh >> 3, h = bh & 7;
    const float inv = __builtin_amdgcn_rcpf(lsum);
    const size_t base = ((size_t)b * S_LEN + s0 + l31) * EMBED + h * HD;
#pragma unroll
    for (int c = 0; c < 4; ++c) {
        const int d0 = c*8 + hi*4;
        v4us p0, p1;
#pragma unroll
        for (int i = 0; i < 4; ++i) {
            p0[i] = (u16)f2bf(o0[c*4+i] * inv);
            p1[i] = (u16)f2bf(o1[c*4+i] * inv);
        }
        *(v4us*)(attn_buf + base + d0)      = p0;
        *(v4us*)(attn_buf + base + 32 + d0) = p1;
    }
}

// ---------------------------------------------------------------------------
// Kernel 3: out = attn_buf @ Wo^T + bo  (M=8192, N=512, K=512), fp32 out.
// ---------------------------------------------------------------------------
__global__ __launch_bounds__(256) void oproj_kernel(
    const u16* __restrict__ attn_buf, const u16* __restrict__ wo_bf,
    const float* __restrict__ bo, float* __restrict__ out)
{
    const int tid = threadIdx.x;
    const int lane = tid & 63;
    const int w = tid >> 6;
    const int lr = lane & 15;
    const int g  = lane >> 4;
    const int bid = blockIdx.x;
    const int m0 = (bid >> 3)*64 + w*16;
    const int n0 = (bid & 7)*64;

    v4f acc[4];
#pragma unroll
    for (int i = 0; i < 4; ++i) acc[i] = (v4f){0.f,0.f,0.f,0.f};

    for (int kk = 0; kk < EMBED/32; ++kk) {
        const int k0 = kk*32;
        v8s af = *(const v8s*)(attn_buf + (size_t)(m0+lr)*EMBED + k0 + g*8);
#pragma unroll
        for (int nt = 0; nt < 4; ++nt) {
            v8s bf = *(const v8s*)(wo_bf + (size_t)(n0 + nt*16 + lr)*EMBED + k0 + g*8);
            acc[nt] = __builtin_amdgcn_mfma_f32_16x16x32_bf16(af, bf, acc[nt], 0,0,0);
        }
    }
#pragma unroll
    for (int nt = 0; nt < 4; ++nt) {
        float bias = bo[n0 + nt*16 + lr];
#pragma unroll
        for (int r = 0; r < 4; ++r) {
            out[(size_t)(m0 + g*4 + r)*EMBED + n0 + nt*16 + lr] = acc[nt][r] + bias;
        }
    }
}

extern "C" void kernel_launch(void* const* d_in, const int* in_sizes, int n_in,
                              void* d_out, int out_size, void* d_ws, size_t ws_size,
                              hipStream_t stream)
{
    const float* xv = (const float*)d_in[0];   // values
    const float* xk = (const float*)d_in[1];   // keys
    const float* xq = (const float*)d_in[2];   // query
    const float* Wv = (const float*)d_in[3];
    const float* Wk = (const float*)d_in[4];
    const float* Wq = (const float*)d_in[5];
    const float* Wo = (const float*)d_in[6];
    const float* bo = (const float*)d_in[7];

    char* ws = (char*)d_ws;
    u16* q_bf   = (u16*)(ws + OFF_Q);
    u16* k_bf   = (u16*)(ws + OFF_K);
    u16* vt_bf  = (u16*)(ws + OFF_VT);
    u16* at_buf = (u16*)(ws + OFF_AT);
    u16* wo_bf  = (u16*)(ws + OFF_WO);

    proj_kernel<<<1024, 256, 0, stream>>>(xv, xk, xq, Wv, Wk, Wq, Wo,
                                          q_bf, k_bf, vt_bf, wo_bf);
    flash_kernel<<<512, 256, 0, stream>>>(q_bf, k_bf, vt_bf, at_buf);
    oproj_kernel<<<1024, 256, 0, stream>>>(at_buf, wo_bf, bo, (float*)d_out);
}